// Round 8
// baseline (354.386 us; speedup 1.0000x reference)
//
#include <hip/hip_runtime.h>
#include <hip/hip_bf16.h>
#include <math.h>

#define HH 96
#define WWID 96
#define HW 9216
#define CC 256
#define BB 2
#define PROW 104
#define PCOL 128
#define PPX (PROW * PCOL)   // 13312

typedef float f32x4 __attribute__((ext_vector_type(4)));
typedef _Float16 f16x8 __attribute__((ext_vector_type(8)));
typedef _Float16 h2v __attribute__((ext_vector_type(2)));
typedef _Float16 h4v __attribute__((ext_vector_type(4)));

__device__ inline unsigned int pack2h(float a, float b) {
  unsigned short ua = __builtin_bit_cast(unsigned short, (_Float16)a);
  unsigned short ub = __builtin_bit_cast(unsigned short, (_Float16)b);
  return (unsigned int)ua | ((unsigned int)ub << 16);
}

#if defined(__has_builtin)
#if __has_builtin(__builtin_amdgcn_fdot2)
#define FDOT2(a, b, c) __builtin_amdgcn_fdot2((a), (b), (c), false)
#endif
#endif
#ifndef FDOT2
#define FDOT2(a, b, c) ((c) + (float)(a).x * (float)(b).x + (float)(a).y * (float)(b).y)
#endif

// async 16B global->LDS: lds dest = wave-uniform base + lane*16
__device__ inline void gload_lds16(const void* g, void* l) {
  __builtin_amdgcn_global_load_lds(
      (const __attribute__((address_space(1))) void*)g,
      (__attribute__((address_space(3))) void*)l, 16, 0, 0);
}

// merged: in_w transpose (blocks 0..255) + conv3x3 weight pack x4 (blocks 256+)
__global__ void k_prep(const float* __restrict__ in_w, float* __restrict__ wT,
                       const float* __restrict__ ow1, const float* __restrict__ ob1,
                       const float* __restrict__ mw1, const float* __restrict__ mb1,
                       const float* __restrict__ ow2, const float* __restrict__ ob2,
                       const float* __restrict__ mw2, const float* __restrict__ mb2,
                       const float* __restrict__ ow4, const float* __restrict__ ob4,
                       const float* __restrict__ mw4, const float* __restrict__ mb4,
                       _Float16* __restrict__ Whf, float* __restrict__ Ball) {
  int bx = blockIdx.x;
  int t = threadIdx.x;
  if (bx < 256) {
    wT[bx * CC + t] = in_w[t * CC + bx];
    return;
  }
  int idx0 = (bx - 256) * 1024 + t * 4;
  if (idx0 >= 3 * 256 * 2304) return;
  #pragma unroll
  for (int u = 0; u < 4; ++u) {
    int idx = idx0 + u;
    int d = idx / (256 * 2304);
    int rem = idx - d * 256 * 2304;
    int co = rem / 2304;
    int k = rem - co * 2304;
    int j = k >> 8, ci = k & 255;
    const float* ow = d == 0 ? ow1 : (d == 1 ? ow2 : ow4);
    const float* mw = d == 0 ? mw1 : (d == 1 ? mw2 : mw4);
    float v = 0.f;
    if (co < 144) v = ow[co * 2304 + ci * 9 + j];
    else if (co < 216) v = mw[(co - 144) * 2304 + ci * 9 + j];
    Whf[idx] = (_Float16)v;
    if (idx < 768) {
      int dd = idx >> 8, cc = idx & 255;
      const float* obv = dd == 0 ? ob1 : (dd == 1 ? ob2 : ob4);
      const float* mbv = dd == 0 ? mb1 : (dd == 1 ? mb2 : mb4);
      float bv = 0.f;
      if (cc < 144) bv = obv[cc];
      else if (cc < 216) bv = mbv[cc - 144];
      Ball[idx] = bv;
    }
  }
}

// conv1x1 + LayerNorm for the query + FUSED sim0 (pooled grouped 1x1).
__global__ void k_conv1_ln_q(const float* __restrict__ qin, const float* __restrict__ wT,
                             const float* __restrict__ in_b, const float* __restrict__ ln_g,
                             const float* __restrict__ ln_b, const float* __restrict__ pooled,
                             _Float16* __restrict__ qpad, float* __restrict__ sim) {
  int bx = blockIdx.x;
  int b = bx / 288;
  int hw0 = (bx % 288) * 32;
  int t = threadIdx.x;
  int lane = t & 63;
  int wv_id = t >> 6;
  __shared__ float xs[32 * 260];
  const float* qb = qin + (size_t)b * CC * HW;
  #pragma unroll
  for (int i = 0; i < 32; ++i) {
    int idx = t + i * 256;
    int p = idx & 31;
    int k = idx >> 5;
    xs[p * 260 + k] = qb[k * HW + hw0 + p];
  }
  __syncthreads();
  float acc[8][4];
  #pragma unroll
  for (int p = 0; p < 8; ++p) { acc[p][0]=0.f; acc[p][1]=0.f; acc[p][2]=0.f; acc[p][3]=0.f; }
  const float4* wT4 = (const float4*)wT;
  int p0 = wv_id * 8;
  for (int k = 0; k < 256; k += 4) {
    float4 w0 = wT4[(k + 0) * 64 + lane];
    float4 w1 = wT4[(k + 1) * 64 + lane];
    float4 w2 = wT4[(k + 2) * 64 + lane];
    float4 w3 = wT4[(k + 3) * 64 + lane];
    #pragma unroll
    for (int p = 0; p < 8; ++p) {
      float4 xv = *(const float4*)&xs[(p0 + p) * 260 + k];
      acc[p][0] += w0.x * xv.x + w1.x * xv.y + w2.x * xv.z + w3.x * xv.w;
      acc[p][1] += w0.y * xv.x + w1.y * xv.y + w2.y * xv.z + w3.y * xv.w;
      acc[p][2] += w0.z * xv.x + w1.z * xv.y + w2.z * xv.z + w3.z * xv.w;
      acc[p][3] += w0.w * xv.x + w1.w * xv.y + w2.w * xv.z + w3.w * xv.w;
    }
  }
  float4 bb = ((const float4*)in_b)[lane];
  float4 g4 = ((const float4*)ln_g)[lane];
  float4 b4 = ((const float4*)ln_b)[lane];
  int lg = lane >> 5;
  int lc = lane & 31;
  const float4* pp = (const float4*)(pooled + (size_t)b * 768 + (lg * 3) * 128);
  float4 pr0 = pp[lc];
  float4 pr1 = pp[32 + lc];
  float4 pr2 = pp[64 + lc];
  #pragma unroll
  for (int p = 0; p < 8; ++p) {
    float y0 = acc[p][0] + bb.x, y1 = acc[p][1] + bb.y;
    float y2 = acc[p][2] + bb.z, y3 = acc[p][3] + bb.w;
    float s1 = y0 + y1 + y2 + y3;
    float s2 = y0*y0 + y1*y1 + y2*y2 + y3*y3;
    #pragma unroll
    for (int off = 32; off; off >>= 1) { s1 += __shfl_xor(s1, off); s2 += __shfl_xor(s2, off); }
    float mu = s1 * (1.f / 256.f);
    float rstd = rsqrtf(s2 * (1.f / 256.f) - mu * mu + 1e-5f);
    float4 o;
    o.x = (y0 - mu) * rstd * g4.x + b4.x;
    o.y = (y1 - mu) * rstd * g4.y + b4.y;
    o.z = (y2 - mu) * rstd * g4.z + b4.z;
    o.w = (y3 - mu) * rstd * g4.w + b4.w;
    int hw = hw0 + p0 + p;
    int hh = hw / 96, ww = hw - hh * 96;
    int ppx = (hh + 4) * PCOL + ww + 4;
    struct alignas(8) h4 { _Float16 h[4]; };
    h4 oh;
    oh.h[0] = (_Float16)o.x; oh.h[1] = (_Float16)o.y;
    oh.h[2] = (_Float16)o.z; oh.h[3] = (_Float16)o.w;
    *(h4*)(qpad + ((size_t)b * PPX + ppx) * CC + lane * 4) = oh;
    float r0 = pr0.x * o.x + pr0.y * o.y + pr0.z * o.z + pr0.w * o.w;
    float r1 = pr1.x * o.x + pr1.y * o.y + pr1.z * o.z + pr1.w * o.w;
    float r2 = pr2.x * o.x + pr2.y * o.y + pr2.z * o.z + pr2.w * o.w;
    #pragma unroll
    for (int off = 16; off; off >>= 1) {
      r0 += __shfl_xor(r0, off);
      r1 += __shfl_xor(r1, off);
      r2 += __shfl_xor(r2, off);
    }
    if (lc == 0) {
      size_t base = ((size_t)b * 24 + lg * 3) * HW + hw;
      sim[base] = r0;
      sim[base + HW] = r1;
      sim[base + 2 * HW] = r2;
    }
  }
}

// supports: conv1x1 + LN per (b,e) image of 9 positions; also pooled max.
__global__ void k_conv1_ln_s(const float* __restrict__ sup, const float* __restrict__ wT,
                             const float* __restrict__ in_b, const float* __restrict__ ln_g,
                             const float* __restrict__ ln_b, float* __restrict__ s_ln,
                             float* __restrict__ pooled) {
  int img = blockIdx.x;  // b*3+e
  int t = threadIdx.x;
  int wv = t >> 6;
  int lane = t & 63;
  __shared__ float xs[2304];
  __shared__ float r1s[4][9], r2s[4][9];
  #pragma unroll
  for (int p = 0; p < 9; ++p) xs[t * 9 + p] = sup[(size_t)img * 2304 + t * 9 + p];
  __syncthreads();
  float acc[9];
  #pragma unroll
  for (int p = 0; p < 9; ++p) acc[p] = 0.f;
  for (int k = 0; k < 256; ++k) {
    float wv_ = wT[k * CC + t];
    #pragma unroll
    for (int p = 0; p < 9; ++p) acc[p] += wv_ * xs[k * 9 + p];
  }
  float bias = in_b[t];
  #pragma unroll
  for (int p = 0; p < 9; ++p) acc[p] += bias;
  #pragma unroll
  for (int p = 0; p < 9; ++p) {
    float s1 = acc[p];
    float s2 = acc[p] * acc[p];
    #pragma unroll
    for (int off = 32; off; off >>= 1) { s1 += __shfl_xor(s1, off); s2 += __shfl_xor(s2, off); }
    if (lane == 0) { r1s[wv][p] = s1; r2s[wv][p] = s2; }
  }
  __syncthreads();
  float g = ln_g[t], be = ln_b[t];
  float vals[9];
  #pragma unroll
  for (int p = 0; p < 9; ++p) {
    float s1 = r1s[0][p] + r1s[1][p] + r1s[2][p] + r1s[3][p];
    float s2 = r2s[0][p] + r2s[1][p] + r2s[2][p] + r2s[3][p];
    float mu = s1 * (1.f / 256.f);
    float var = s2 * (1.f / 256.f) - mu * mu;
    float rstd = rsqrtf(var + 1e-5f);
    vals[p] = (acc[p] - mu) * rstd * g + be;
  }
  #pragma unroll
  for (int p = 0; p < 9; ++p) s_ln[(size_t)img * 2304 + t * 9 + p] = vals[p];
  float mx = vals[0];
  #pragma unroll
  for (int p = 1; p < 9; ++p) mx = fmaxf(mx, vals[p]);
  int b = img / 3, e = img % 3;
  pooled[((size_t)b * 6 + e * 2 + (t >> 7)) * 128 + (t & 127)] = mx;
}

// ---------------------------------------------------------------------------
// conv3x3 implicit GEMM, 256x256 tile, BK=64, 8 waves, 8-phase schedule with
// counted vmcnt(4) fences, XOR-swizzled LDS, setprio around MFMA clusters.
// FUSED EPILOGUE: taps softmax + record generation from LDS-stashed C.
// ---------------------------------------------------------------------------

#define BAR() __builtin_amdgcn_s_barrier()
#define SCHEDB() __builtin_amdgcn_sched_barrier(0)
#define VMCNT(N) asm volatile("s_waitcnt vmcnt(" #N ")" ::: "memory")

#define MMA_ONE(M, N, S, QM, QN) \
  acc[(QM)*4+(M)][(QN)*2+(N)] = __builtin_amdgcn_mfma_f32_16x16x32_f16( \
      af[M][S], bf[(QN)*2+(N)][S], acc[(QM)*4+(M)][(QN)*2+(N)], 0, 0, 0);

#define MMA_Q(QM, QN) { \
  __builtin_amdgcn_s_setprio(1); \
  MMA_ONE(0,0,0,QM,QN) MMA_ONE(1,0,0,QM,QN) MMA_ONE(2,0,0,QM,QN) MMA_ONE(3,0,0,QM,QN) \
  MMA_ONE(0,1,0,QM,QN) MMA_ONE(1,1,0,QM,QN) MMA_ONE(2,1,0,QM,QN) MMA_ONE(3,1,0,QM,QN) \
  MMA_ONE(0,0,1,QM,QN) MMA_ONE(1,0,1,QM,QN) MMA_ONE(2,0,1,QM,QN) MMA_ONE(3,0,1,QM,QN) \
  MMA_ONE(0,1,1,QM,QN) MMA_ONE(1,1,1,QM,QN) MMA_ONE(2,1,1,QM,QN) MMA_ONE(3,1,1,QM,QN) \
  __builtin_amdgcn_s_setprio(0); }

#define LDA(BUF, QM) { \
  const char* p_ = smemB + (BUF) * 65536 + (wm * 128 + (QM) * 64 + l15) * 128; \
  af[0][0] = *(const f16x8*)(p_ + 0*2048 + rc0); af[0][1] = *(const f16x8*)(p_ + 0*2048 + rc1); \
  af[1][0] = *(const f16x8*)(p_ + 1*2048 + rc0); af[1][1] = *(const f16x8*)(p_ + 1*2048 + rc1); \
  af[2][0] = *(const f16x8*)(p_ + 2*2048 + rc0); af[2][1] = *(const f16x8*)(p_ + 2*2048 + rc1); \
  af[3][0] = *(const f16x8*)(p_ + 3*2048 + rc0); af[3][1] = *(const f16x8*)(p_ + 3*2048 + rc1); }

#define LDB(BUF, QN) { \
  const char* p_ = smemB + (BUF) * 65536 + 32768 + (wn * 64 + (QN) * 32 + l15) * 128; \
  bf[(QN)*2+0][0] = *(const f16x8*)(p_ + 0*2048 + rc0); bf[(QN)*2+0][1] = *(const f16x8*)(p_ + 0*2048 + rc1); \
  bf[(QN)*2+1][0] = *(const f16x8*)(p_ + 1*2048 + rc0); bf[(QN)*2+1][1] = *(const f16x8*)(p_ + 1*2048 + rc1); }

#define STAGEA(TILE, Q) { \
  gload_lds16(aBase + (size_t)((Q) * 64) * 2304 + (TILE) * 64, \
              smemB + ((TILE) & 1) * 65536 + (((Q) * 64 + wv * 8) * 128)); \
  gload_lds16(aBase + (size_t)(128 + (Q) * 64) * 2304 + (TILE) * 64, \
              smemB + ((TILE) & 1) * 65536 + ((128 + (Q) * 64 + wv * 8) * 128)); }

#define STAGEB(TILE, Q, PPX0, PPX1) { \
  int j_ = (TILE) >> 2; \
  int offp_ = (j_ / 3 - 1) * PCOL + (j_ % 3) - 1; \
  int cb_ = ((TILE) & 3) * 64; \
  int rs_ = (wv >> 2) * 64 + (Q) * 32 + (wv & 3) * 8; \
  gload_lds16(bBase + (size_t)((PPX0) + offp_) * CC + cb_, \
              smemB + ((TILE) & 1) * 65536 + 32768 + (rs_ * 128)); \
  gload_lds16(bBase + (size_t)((PPX1) + offp_) * CC + cb_, \
              smemB + ((TILE) & 1) * 65536 + 32768 + ((128 + rs_) * 128)); }

__global__ void __launch_bounds__(512) k_conv3_mfma8(
    const _Float16* __restrict__ qpad, const _Float16* __restrict__ Whf,
    const float* __restrict__ Ball, unsigned int* __restrict__ taprec) {
  int nb = blockIdx.x;        // 36 px tiles of 256
  int z = blockIdx.y;         // 6 = 3 d x 2 b
  int d = z >> 1, b = z & 1;
  int t = threadIdx.x;
  int lane = t & 63, wv = t >> 6;        // 8 waves
  int wm = wv >> 2, wn = wv & 3;         // 2 x 4 wave grid -> 128x64 per wave
  int quad = lane >> 4, l15 = lane & 15;
  int l8 = lane >> 3, c7 = lane & 7;

  __shared__ _Float16 __attribute__((aligned(16))) smem[65536];  // 128 KiB
  char* smemB = (char*)smem;

  const _Float16* Wd = Whf + (size_t)d * 256 * 2304;
  const _Float16* qb = qpad + (size_t)b * PPX * CC;

  int scol = ((c7 ^ l8) << 3);                   // source col offset (halfs)
  int rc0 = ((quad ^ (l15 & 7)) << 4);           // read byte col, k-slice 0
  int rc1 = (((4 | quad) ^ (l15 & 7)) << 4);     // k-slice 1

  const _Float16* aBase = Wd + (size_t)(wv * 8 + l8) * 2304 + scol;
  const _Float16* bBase = qb + scol;

  int ppx00, ppx01, ppx10, ppx11;
  {
    int rbase = (wv >> 2) * 64 + (wv & 3) * 8 + l8;
    int px, hh, ww;
    px = nb * 256 + rbase;             hh = px / 96; ww = px - hh * 96; ppx00 = (hh + 4) * PCOL + ww + 4;
    px = nb * 256 + 128 + rbase;       hh = px / 96; ww = px - hh * 96; ppx01 = (hh + 4) * PCOL + ww + 4;
    px = nb * 256 + 32 + rbase;        hh = px / 96; ww = px - hh * 96; ppx10 = (hh + 4) * PCOL + ww + 4;
    px = nb * 256 + 160 + rbase;       hh = px / 96; ww = px - hh * 96; ppx11 = (hh + 4) * PCOL + ww + 4;
  }

  f32x4 acc[8][4];
  #pragma unroll
  for (int i = 0; i < 8; ++i)
    #pragma unroll
    for (int j = 0; j < 4; ++j) acc[i][j] = (f32x4){0.f, 0.f, 0.f, 0.f};

  f16x8 af[4][2], bf[4][2];

  STAGEA(0, 0);
  STAGEB(0, 1, ppx10, ppx11);
  STAGEA(0, 1);
  STAGEB(0, 0, ppx00, ppx01);
  STAGEA(1, 0);
  STAGEB(1, 1, ppx10, ppx11);
  VMCNT(4);
  BAR();
  SCHEDB();

  #pragma unroll 1
  for (int ii = 0; ii < 17; ++ii) {
    int ta = 2 * ii + 1, tb = 2 * ii + 2, tc = 2 * ii + 3;
    LDA(0, 0) LDB(0, 0)
    STAGEA(ta, 1);
    BAR(); MMA_Q(0, 0); BAR();
    LDB(0, 1)
    STAGEB(ta, 0, ppx00, ppx01);
    BAR(); MMA_Q(0, 1); BAR();
    LDA(0, 1)
    STAGEA(tb, 0);
    BAR(); MMA_Q(1, 1); BAR();
    STAGEB(tb, 1, ppx10, ppx11);
    VMCNT(4);
    BAR(); SCHEDB(); MMA_Q(1, 0); BAR();
    LDA(1, 0) LDB(1, 0)
    STAGEA(tb, 1);
    BAR(); MMA_Q(0, 0); BAR();
    LDB(1, 1)
    STAGEB(tb, 0, ppx00, ppx01);
    BAR(); MMA_Q(0, 1); BAR();
    LDA(1, 1)
    STAGEA(tc, 0);
    BAR(); MMA_Q(1, 1); BAR();
    STAGEB(tc, 1, ppx10, ppx11);
    VMCNT(4);
    BAR(); SCHEDB(); MMA_Q(1, 0); BAR();
  }

  LDA(0, 0) LDB(0, 0)
  STAGEA(35, 1);
  BAR(); MMA_Q(0, 0); BAR();
  LDB(0, 1)
  STAGEB(35, 0, ppx00, ppx01);
  BAR(); MMA_Q(0, 1); BAR();
  LDA(0, 1)
  BAR(); MMA_Q(1, 1); BAR();
  VMCNT(0);
  BAR(); SCHEDB(); MMA_Q(1, 0); BAR();
  LDA(1, 0) LDB(1, 0)
  BAR(); MMA_Q(0, 0); BAR();
  LDB(1, 1)
  BAR(); MMA_Q(0, 1); BAR();
  LDA(1, 1)
  BAR(); MMA_Q(1, 1); BAR();
  MMA_Q(1, 0);

  // ---------------- fused taps epilogue ----------------
  BAR();
  float* cs = (float*)smemB;
  const float* Bd = Ball + d * 256;
  unsigned int* tzo = taprec + (size_t)z * 72 * HW * 3;
  int sub = t & 7;
  int pxq = t >> 3;            // 0..63
  int dil = 1 << d;

  #pragma unroll 1
  for (int H = 0; H < 2; ++H) {
    if ((wn >> 1) == H) {
      #pragma unroll
      for (int mi = 0; mi < 8; ++mi) {
        int c2 = wm * 128 + mi * 16 + quad * 4;
        if (c2 < 216) {
          float4 bq = *(const float4*)(Bd + c2);
          #pragma unroll
          for (int ni = 0; ni < 4; ++ni) {
            int pl = (wn & 1) * 64 + ni * 16 + l15;
            f32x4 v = acc[mi][ni];
            float* cp = &cs[pl * 225 + c2];
            cp[0] = v[0] + bq.x; cp[1] = v[1] + bq.y;
            cp[2] = v[2] + bq.z; cp[3] = v[3] + bq.w;
          }
        }
      }
    }
    BAR();
    #pragma unroll 1
    for (int p = 0; p < 2; ++p) {
      int pl = p * 64 + pxq;                       // 0..127
      int px = nb * 256 + H * 128 + pl;
      const float* cr = &cs[pl * 225];
      float lg[9];
      float mx = -1e30f;
      #pragma unroll
      for (int j = 0; j < 9; ++j) {
        lg[j] = cr[144 + sub + 8 * j];
        mx = fmaxf(mx, lg[j]);
      }
      mx = fmaxf(mx, __shfl_xor(mx, 1));
      mx = fmaxf(mx, __shfl_xor(mx, 2));
      mx = fmaxf(mx, __shfl_xor(mx, 4));
      float s = 0.f;
      #pragma unroll
      for (int j = 0; j < 9; ++j) s += __expf(lg[j] - mx);
      s += __shfl_xor(s, 1);
      s += __shfl_xor(s, 2);
      s += __shfl_xor(s, 4);
      float rinv = 1.f / s;
      int h = px / WWID, w = px - h * WWID;
      int k = sub;               // k = tk % 9, tk = sub + 8j
      #pragma unroll
      for (int j = 0; j < 9; ++j) {
        int tk = sub + 8 * j;
        float dy = cr[tk * 2 + 0];
        float dx = cr[tk * 2 + 1];
        float m = __expf(lg[j] - mx) * rinv;
        float py = (float)(h + (k / 3) * dil - dil) + dy;
        float pxx = (float)(w + (k % 3) * dil - dil) + dx;
        float y0f = floorf(py), x0f = floorf(pxx);
        int y0 = (int)y0f, x0 = (int)x0f;
        float wy = py - y0f, wx = pxx - x0f;
        bool vy0 = (unsigned)y0 < 96u, vy1 = (unsigned)(y0 + 1) < 96u;
        bool vx0 = (unsigned)x0 < 96u, vx1 = (unsigned)(x0 + 1) < 96u;
        float w00 = (vy0 && vx0) ? (1.f - wy) * (1.f - wx) * m : 0.f;
        float w01 = (vy0 && vx1) ? (1.f - wy) * wx * m : 0.f;
        float w10 = (vy1 && vx0) ? wy * (1.f - wx) * m : 0.f;
        float w11 = (vy1 && vx1) ? wy * wx * m : 0.f;
        int iy = min(max(y0 + 4, 0), 102);
        int ix = min(max(x0 + 4, 0), 126);
        unsigned int* r = tzo + ((size_t)tk * HW + px) * 3;
        r[0] = pack2h(w00, w01);
        r[1] = pack2h(w10, w11);
        r[2] = (unsigned int)(iy * PCOL + ix);
        k += 8; if (k >= 9) k -= 9;
      }
    }
    BAR();
  }
}

// deformable conv v9: 4 ch/lane (8B dwordx2 gathers), 4 ogs spread across the
// 32-lane group (og_in = lane>>3) -> single og pass, VMEM instrs halved
// (288 -> 144/thread). Records LDS rows padded to 100 dwords (bank-disjoint
// per og group). XCD slab swizzle retained.
#define DO_P4(U0, U1, IDX, P) { \
  h2v u0_ = __builtin_bit_cast(h2v, (U0)); \
  h2v u1_ = __builtin_bit_cast(h2v, (U1)); \
  const h4v* b0_ = qc + (size_t)(IDX) * 64; \
  h4v q00_ = b0_[0], q01_ = b0_[64]; \
  h4v q10_ = b0_[8192], q11_ = b0_[8192 + 64]; \
  h4v s_ = q00_ * (h4v){u0_.x, u0_.x, u0_.x, u0_.x} \
         + q01_ * (h4v){u0_.y, u0_.y, u0_.y, u0_.y} \
         + q10_ * (h4v){u1_.x, u1_.x, u1_.x, u1_.x} \
         + q11_ * (h4v){u1_.y, u1_.y, u1_.y, u1_.y}; \
  uint2 su_ = __builtin_bit_cast(uint2, s_); \
  h2v slo_ = __builtin_bit_cast(h2v, su_.x); \
  h2v shi_ = __builtin_bit_cast(h2v, su_.y); \
  acc[P][0] = FDOT2(wr0lo, slo_, acc[P][0]); \
  acc[P][0] = FDOT2(wr0hi, shi_, acc[P][0]); \
  acc[P][1] = FDOT2(wr1lo, slo_, acc[P][1]); \
  acc[P][1] = FDOT2(wr1hi, shi_, acc[P][1]); \
  acc[P][2] = FDOT2(wr2lo, slo_, acc[P][2]); \
  acc[P][2] = FDOT2(wr2hi, shi_, acc[P][2]); }

__global__ void __launch_bounds__(256) k_deform(
    const _Float16* __restrict__ qpad, const unsigned int* __restrict__ taprec,
    const float* __restrict__ s_ln, float* __restrict__ sim) {
  // linear grid 3456 = 8 slabs (XCD via dispatch round-robin) x 432
  int bid = blockIdx.x;
  int slab = bid & 7;
  int j = bid >> 3;                    // 0..431
  int z = j / 72;                      // 6
  int rem = j - z * 72;
  int yhalf = rem / 36;                // 0: og 0..3, 1: og 4..7
  int segin = rem - yhalf * 36;        // 36
  int seg = slab * 36 + segin;         // 288 px segments of 32
  int d_idx = z >> 1, b = z & 1;
  int t = threadIdx.x;
  int g = t >> 5, lane = t & 31;
  int og_in = lane >> 3;               // 4 ogs per 32-lane group
  int l8c = lane & 7;                  // 8 ch-lanes x 4 ch each
  __shared__ _Float16 __attribute__((aligned(16))) wh[9 * 384];  // [9 k][384 ch]
  __shared__ unsigned int __attribute__((aligned(16))) rlds[36 * 100];  // [36 tk][96+4pad]
  int px0 = seg * 32;
  int tkbase = yhalf * 36;
  const unsigned int* tz = taprec + (size_t)z * 72 * HW * 3;
  for (int i2 = t; i2 < 3456; i2 += 256) {
    int c = i2 / 9, k = i2 % 9;
    wh[k * 384 + c] = (_Float16)s_ln[(size_t)b * 6912 + yhalf * 3456 + i2];
  }
  for (int i2 = t; i2 < 3456; i2 += 256) {
    int tko = i2 / 96, dw = i2 - tko * 96;
    rlds[tko * 100 + dw] = tz[((size_t)(tkbase + tko) * HW + px0) * 3 + dw];
  }
  __syncthreads();
  int pg = g * 4;
  int pxb = px0 + pg;
  const h4v* whp = (const h4v*)wh;
  const _Float16* qb = qpad + (size_t)b * PPX * CC;

  int wcol = og_in * 32 + l8c * 4;              // 0..124 within the 384-col half
  int qch = yhalf * 128 + wcol;                 // q channel (mult of 4)
  int tko0 = og_in * 9;                         // tk - tkbase
  const h4v* qc = (const h4v*)(qb + qch);       // h4v units; px stride = 64

  float acc[4][3];
  #pragma unroll
  for (int p = 0; p < 4; ++p)
    #pragma unroll
    for (int r = 0; r < 3; ++r) acc[p][r] = 0.f;

  #pragma unroll 3
  for (int k = 0; k < 9; ++k) {
    const uint4* rr4 = (const uint4*)&rlds[(tko0 + k) * 100 + pg * 3];
    uint4 ra = rr4[0];
    uint4 rb = rr4[1];
    uint4 rc = rr4[2];
    int wbase = k * 96 + (wcol >> 2);           // h4v index
    h4v w0 = whp[wbase];
    h4v w1 = whp[wbase + 32];
    h4v w2 = whp[wbase + 64];
    uint2 w0u = __builtin_bit_cast(uint2, w0);
    uint2 w1u = __builtin_bit_cast(uint2, w1);
    uint2 w2u = __builtin_bit_cast(uint2, w2);
    h2v wr0lo = __builtin_bit_cast(h2v, w0u.x), wr0hi = __builtin_bit_cast(h2v, w0u.y);
    h2v wr1lo = __builtin_bit_cast(h2v, w1u.x), wr1hi = __builtin_bit_cast(h2v, w1u.y);
    h2v wr2lo = __builtin_bit_cast(h2v, w2u.x), wr2hi = __builtin_bit_cast(h2v, w2u.y);
    DO_P4(ra.x, ra.y, ra.z, 0)
    DO_P4(ra.w, rb.x, rb.y, 1)
    DO_P4(rb.z, rb.w, rc.x, 2)
    DO_P4(rc.y, rc.z, rc.w, 3)
  }

  #pragma unroll
  for (int p = 0; p < 4; ++p) {
    #pragma unroll
    for (int r = 0; r < 3; ++r) {
      float v = acc[p][r];
      #pragma unroll
      for (int off = 16; off; off >>= 1) v += __shfl_down(v, off, 32);
      if (lane == 0)
        sim[((size_t)b * 24 + 6 + 6 * d_idx + yhalf * 3 + r) * HW + pxb + p] = v;
    }
  }
}

// out 1x1 conv: 4 co per block -> 4x sim-read reuse. grid (36, 64, B).
__global__ void k_outconv(const float* __restrict__ sim, const float* __restrict__ out_w,
                          const float* __restrict__ out_b, float* __restrict__ out) {
  int hw = blockIdx.x * 256 + threadIdx.x;
  int coq = blockIdx.y * 4;
  int b = blockIdx.z;
  const float* simb = sim + (size_t)b * 24 * HW;
  float a0 = out_b[coq + 0];
  float a1 = out_b[coq + 1];
  float a2 = out_b[coq + 2];
  float a3 = out_b[coq + 3];
  #pragma unroll
  for (int r = 0; r < 24; ++r) {
    float sv = simb[(size_t)r * HW + hw];
    a0 += out_w[(coq + 0) * 24 + r] * sv;
    a1 += out_w[(coq + 1) * 24 + r] * sv;
    a2 += out_w[(coq + 2) * 24 + r] * sv;
    a3 += out_w[(coq + 3) * 24 + r] * sv;
  }
  size_t base = ((size_t)b * CC + coq) * HW + hw;
  out[base] = a0;
  out[base + HW] = a1;
  out[base + 2 * HW] = a2;
  out[base + 3 * HW] = a3;
}

extern "C" void kernel_launch(void* const* d_in, const int* in_sizes, int n_in,
                              void* d_out, int out_size, void* d_ws, size_t ws_size,
                              hipStream_t stream) {
  const float* querys = (const float*)d_in[0];
  const float* sup    = (const float*)d_in[1];
  const float* in_w   = (const float*)d_in[2];
  const float* in_b   = (const float*)d_in[3];
  const float* ln_g   = (const float*)d_in[4];
  const float* ln_b   = (const float*)d_in[5];
  const float* out_w  = (const float*)d_in[6];
  const float* out_b  = (const float*)d_in[7];
  const float* ow1 = (const float*)d_in[8];
  const float* ob1 = (const float*)d_in[9];
  const float* mw1 = (const float*)d_in[10];
  const float* mb1 = (const float*)d_in[11];
  const float* ow2 = (const float*)d_in[12];
  const float* ob2 = (const float*)d_in[13];
  const float* mw2 = (const float*)d_in[14];
  const float* mb2 = (const float*)d_in[15];
  const float* ow4 = (const float*)d_in[16];
  const float* ob4 = (const float*)d_in[17];
  const float* mw4 = (const float*)d_in[18];
  const float* mb4 = (const float*)d_in[19];
  float* out = (float*)d_out;

  float* ws_f   = (float*)d_ws;
  float* wT     = ws_f;                              // 65536 floats
  _Float16* Whf = (_Float16*)(wT + 65536);           // 884736 float slots
  float* Ball   = (float*)(Whf + 3 * 256 * 2304);    // 768 (pad 1024)
  _Float16* qpad = (_Float16*)(Ball + 1024);         // 3407872 float slots
  float* s_ln   = (float*)(qpad + (size_t)BB * PPX * CC);  // 13824
  float* pooled = s_ln + 13824;                      // 1536
  unsigned int* taprec = (unsigned int*)(pooled + 1536);   // 11943936 dwords
  float* sim    = (float*)(taprec + (size_t)6 * 72 * HW * 3);  // 442368

  hipMemsetAsync(qpad, 0, (size_t)BB * PPX * CC * sizeof(_Float16), stream);
  k_prep<<<dim3(256 + 1728), dim3(256), 0, stream>>>(
      in_w, wT, ow1, ob1, mw1, mb1, ow2, ob2, mw2, mb2, ow4, ob4, mw4, mb4, Whf, Ball);
  k_conv1_ln_s<<<dim3(6), dim3(256), 0, stream>>>(sup, wT, in_b, ln_g, ln_b, s_ln, pooled);
  k_conv1_ln_q<<<dim3(576), dim3(256), 0, stream>>>(querys, wT, in_b, ln_g, ln_b, pooled, qpad, sim);
  k_conv3_mfma8<<<dim3(36, 6), dim3(512), 0, stream>>>(qpad, Whf, Ball, taprec);
  k_deform<<<dim3(3456), dim3(256), 0, stream>>>(qpad, taprec, s_ln, sim);
  k_outconv<<<dim3(36, 64, BB), dim3(256), 0, stream>>>(sim, out_w, out_b, out);
}

// Round 9
// 336.777 us; speedup vs baseline: 1.0523x; 1.0523x over previous
//
#include <hip/hip_runtime.h>
#include <hip/hip_bf16.h>
#include <math.h>

#define HH 96
#define WWID 96
#define HW 9216
#define CC 256
#define BB 2
#define PROW 104
#define PCOL 128
#define PPX (PROW * PCOL)   // 13312

typedef float f32x4 __attribute__((ext_vector_type(4)));
typedef _Float16 f16x8 __attribute__((ext_vector_type(8)));
typedef _Float16 h2v __attribute__((ext_vector_type(2)));

__device__ inline unsigned int pack2h(float a, float b) {
  unsigned short ua = __builtin_bit_cast(unsigned short, (_Float16)a);
  unsigned short ub = __builtin_bit_cast(unsigned short, (_Float16)b);
  return (unsigned int)ua | ((unsigned int)ub << 16);
}

#if defined(__has_builtin)
#if __has_builtin(__builtin_amdgcn_fdot2)
#define FDOT2(a, b, c) __builtin_amdgcn_fdot2((a), (b), (c), false)
#endif
#endif
#ifndef FDOT2
#define FDOT2(a, b, c) ((c) + (float)(a).x * (float)(b).x + (float)(a).y * (float)(b).y)
#endif

// async 16B global->LDS: lds dest = wave-uniform base + lane*16
__device__ inline void gload_lds16(const void* g, void* l) {
  __builtin_amdgcn_global_load_lds(
      (const __attribute__((address_space(1))) void*)g,
      (__attribute__((address_space(3))) void*)l, 16, 0, 0);
}

// merged: in_w transpose (blocks 0..255) + conv3x3 weight pack x4 (blocks 256+)
__global__ void k_prep(const float* __restrict__ in_w, float* __restrict__ wT,
                       const float* __restrict__ ow1, const float* __restrict__ ob1,
                       const float* __restrict__ mw1, const float* __restrict__ mb1,
                       const float* __restrict__ ow2, const float* __restrict__ ob2,
                       const float* __restrict__ mw2, const float* __restrict__ mb2,
                       const float* __restrict__ ow4, const float* __restrict__ ob4,
                       const float* __restrict__ mw4, const float* __restrict__ mb4,
                       _Float16* __restrict__ Whf, float* __restrict__ Ball) {
  int bx = blockIdx.x;
  int t = threadIdx.x;
  if (bx < 256) {
    wT[bx * CC + t] = in_w[t * CC + bx];
    return;
  }
  int idx0 = (bx - 256) * 1024 + t * 4;
  if (idx0 >= 3 * 256 * 2304) return;
  #pragma unroll
  for (int u = 0; u < 4; ++u) {
    int idx = idx0 + u;
    int d = idx / (256 * 2304);
    int rem = idx - d * 256 * 2304;
    int co = rem / 2304;
    int k = rem - co * 2304;
    int j = k >> 8, ci = k & 255;
    const float* ow = d == 0 ? ow1 : (d == 1 ? ow2 : ow4);
    const float* mw = d == 0 ? mw1 : (d == 1 ? mw2 : mw4);
    float v = 0.f;
    if (co < 144) v = ow[co * 2304 + ci * 9 + j];
    else if (co < 216) v = mw[(co - 144) * 2304 + ci * 9 + j];
    Whf[idx] = (_Float16)v;
    if (idx < 768) {
      int dd = idx >> 8, cc = idx & 255;
      const float* obv = dd == 0 ? ob1 : (dd == 1 ? ob2 : ob4);
      const float* mbv = dd == 0 ? mb1 : (dd == 1 ? mb2 : mb4);
      float bv = 0.f;
      if (cc < 144) bv = obv[cc];
      else if (cc < 216) bv = mbv[cc - 144];
      Ball[idx] = bv;
    }
  }
}

// conv1x1 + LayerNorm for the query + FUSED sim0 (pooled grouped 1x1).
// Staging loop vectorized to float4 (8 dwordx4 vs 32 dword per thread).
__global__ void k_conv1_ln_q(const float* __restrict__ qin, const float* __restrict__ wT,
                             const float* __restrict__ in_b, const float* __restrict__ ln_g,
                             const float* __restrict__ ln_b, const float* __restrict__ pooled,
                             _Float16* __restrict__ qpad, float* __restrict__ sim) {
  int bx = blockIdx.x;
  int b = bx / 288;
  int hw0 = (bx % 288) * 32;
  int t = threadIdx.x;
  int lane = t & 63;
  int wv_id = t >> 6;
  __shared__ float xs[32 * 260];
  const float* qb = qin + (size_t)b * CC * HW;
  #pragma unroll
  for (int i = 0; i < 8; ++i) {
    int idx = t + i * 256;          // 0..2047: chunk = k*8 + pq
    int k = idx >> 3, pq = idx & 7;
    float4 v = *(const float4*)(qb + (size_t)k * HW + hw0 + pq * 4);
    xs[(pq * 4 + 0) * 260 + k] = v.x;
    xs[(pq * 4 + 1) * 260 + k] = v.y;
    xs[(pq * 4 + 2) * 260 + k] = v.z;
    xs[(pq * 4 + 3) * 260 + k] = v.w;
  }
  __syncthreads();
  float acc[8][4];
  #pragma unroll
  for (int p = 0; p < 8; ++p) { acc[p][0]=0.f; acc[p][1]=0.f; acc[p][2]=0.f; acc[p][3]=0.f; }
  const float4* wT4 = (const float4*)wT;
  int p0 = wv_id * 8;
  for (int k = 0; k < 256; k += 4) {
    float4 w0 = wT4[(k + 0) * 64 + lane];
    float4 w1 = wT4[(k + 1) * 64 + lane];
    float4 w2 = wT4[(k + 2) * 64 + lane];
    float4 w3 = wT4[(k + 3) * 64 + lane];
    #pragma unroll
    for (int p = 0; p < 8; ++p) {
      float4 xv = *(const float4*)&xs[(p0 + p) * 260 + k];
      acc[p][0] += w0.x * xv.x + w1.x * xv.y + w2.x * xv.z + w3.x * xv.w;
      acc[p][1] += w0.y * xv.x + w1.y * xv.y + w2.y * xv.z + w3.y * xv.w;
      acc[p][2] += w0.z * xv.x + w1.z * xv.y + w2.z * xv.z + w3.z * xv.w;
      acc[p][3] += w0.w * xv.x + w1.w * xv.y + w2.w * xv.z + w3.w * xv.w;
    }
  }
  float4 bb = ((const float4*)in_b)[lane];
  float4 g4 = ((const float4*)ln_g)[lane];
  float4 b4 = ((const float4*)ln_b)[lane];
  int lg = lane >> 5;
  int lc = lane & 31;
  const float4* pp = (const float4*)(pooled + (size_t)b * 768 + (lg * 3) * 128);
  float4 pr0 = pp[lc];
  float4 pr1 = pp[32 + lc];
  float4 pr2 = pp[64 + lc];
  #pragma unroll
  for (int p = 0; p < 8; ++p) {
    float y0 = acc[p][0] + bb.x, y1 = acc[p][1] + bb.y;
    float y2 = acc[p][2] + bb.z, y3 = acc[p][3] + bb.w;
    float s1 = y0 + y1 + y2 + y3;
    float s2 = y0*y0 + y1*y1 + y2*y2 + y3*y3;
    #pragma unroll
    for (int off = 32; off; off >>= 1) { s1 += __shfl_xor(s1, off); s2 += __shfl_xor(s2, off); }
    float mu = s1 * (1.f / 256.f);
    float rstd = rsqrtf(s2 * (1.f / 256.f) - mu * mu + 1e-5f);
    float4 o;
    o.x = (y0 - mu) * rstd * g4.x + b4.x;
    o.y = (y1 - mu) * rstd * g4.y + b4.y;
    o.z = (y2 - mu) * rstd * g4.z + b4.z;
    o.w = (y3 - mu) * rstd * g4.w + b4.w;
    int hw = hw0 + p0 + p;
    int hh = hw / 96, ww = hw - hh * 96;
    int ppx = (hh + 4) * PCOL + ww + 4;
    struct alignas(8) h4 { _Float16 h[4]; };
    h4 oh;
    oh.h[0] = (_Float16)o.x; oh.h[1] = (_Float16)o.y;
    oh.h[2] = (_Float16)o.z; oh.h[3] = (_Float16)o.w;
    *(h4*)(qpad + ((size_t)b * PPX + ppx) * CC + lane * 4) = oh;
    float r0 = pr0.x * o.x + pr0.y * o.y + pr0.z * o.z + pr0.w * o.w;
    float r1 = pr1.x * o.x + pr1.y * o.y + pr1.z * o.z + pr1.w * o.w;
    float r2 = pr2.x * o.x + pr2.y * o.y + pr2.z * o.z + pr2.w * o.w;
    #pragma unroll
    for (int off = 16; off; off >>= 1) {
      r0 += __shfl_xor(r0, off);
      r1 += __shfl_xor(r1, off);
      r2 += __shfl_xor(r2, off);
    }
    if (lc == 0) {
      size_t base = ((size_t)b * 24 + lg * 3) * HW + hw;
      sim[base] = r0;
      sim[base + HW] = r1;
      sim[base + 2 * HW] = r2;
    }
  }
}

// supports: conv1x1 + LN per (b,e) image of 9 positions; also pooled max.
__global__ void k_conv1_ln_s(const float* __restrict__ sup, const float* __restrict__ wT,
                             const float* __restrict__ in_b, const float* __restrict__ ln_g,
                             const float* __restrict__ ln_b, float* __restrict__ s_ln,
                             float* __restrict__ pooled) {
  int img = blockIdx.x;  // b*3+e
  int t = threadIdx.x;
  int wv = t >> 6;
  int lane = t & 63;
  __shared__ float xs[2304];
  __shared__ float r1s[4][9], r2s[4][9];
  #pragma unroll
  for (int p = 0; p < 9; ++p) xs[t * 9 + p] = sup[(size_t)img * 2304 + t * 9 + p];
  __syncthreads();
  float acc[9];
  #pragma unroll
  for (int p = 0; p < 9; ++p) acc[p] = 0.f;
  for (int k = 0; k < 256; ++k) {
    float wv_ = wT[k * CC + t];
    #pragma unroll
    for (int p = 0; p < 9; ++p) acc[p] += wv_ * xs[k * 9 + p];
  }
  float bias = in_b[t];
  #pragma unroll
  for (int p = 0; p < 9; ++p) acc[p] += bias;
  #pragma unroll
  for (int p = 0; p < 9; ++p) {
    float s1 = acc[p];
    float s2 = acc[p] * acc[p];
    #pragma unroll
    for (int off = 32; off; off >>= 1) { s1 += __shfl_xor(s1, off); s2 += __shfl_xor(s2, off); }
    if (lane == 0) { r1s[wv][p] = s1; r2s[wv][p] = s2; }
  }
  __syncthreads();
  float g = ln_g[t], be = ln_b[t];
  float vals[9];
  #pragma unroll
  for (int p = 0; p < 9; ++p) {
    float s1 = r1s[0][p] + r1s[1][p] + r1s[2][p] + r1s[3][p];
    float s2 = r2s[0][p] + r2s[1][p] + r2s[2][p] + r2s[3][p];
    float mu = s1 * (1.f / 256.f);
    float var = s2 * (1.f / 256.f) - mu * mu;
    float rstd = rsqrtf(var + 1e-5f);
    vals[p] = (acc[p] - mu) * rstd * g + be;
  }
  #pragma unroll
  for (int p = 0; p < 9; ++p) s_ln[(size_t)img * 2304 + t * 9 + p] = vals[p];
  float mx = vals[0];
  #pragma unroll
  for (int p = 1; p < 9; ++p) mx = fmaxf(mx, vals[p]);
  int b = img / 3, e = img % 3;
  pooled[((size_t)b * 6 + e * 2 + (t >> 7)) * 128 + (t & 127)] = mx;
}

// ---------------------------------------------------------------------------
// conv3x3 implicit GEMM, 256x256 tile, BK=64, 8 waves, 8-phase schedule with
// counted vmcnt(4) fences, XOR-swizzled LDS, setprio around MFMA clusters.
// FUSED EPILOGUE: taps softmax + record generation from LDS-stashed C.
// ---------------------------------------------------------------------------

#define BAR() __builtin_amdgcn_s_barrier()
#define SCHEDB() __builtin_amdgcn_sched_barrier(0)
#define VMCNT(N) asm volatile("s_waitcnt vmcnt(" #N ")" ::: "memory")

#define MMA_ONE(M, N, S, QM, QN) \
  acc[(QM)*4+(M)][(QN)*2+(N)] = __builtin_amdgcn_mfma_f32_16x16x32_f16( \
      af[M][S], bf[(QN)*2+(N)][S], acc[(QM)*4+(M)][(QN)*2+(N)], 0, 0, 0);

#define MMA_Q(QM, QN) { \
  __builtin_amdgcn_s_setprio(1); \
  MMA_ONE(0,0,0,QM,QN) MMA_ONE(1,0,0,QM,QN) MMA_ONE(2,0,0,QM,QN) MMA_ONE(3,0,0,QM,QN) \
  MMA_ONE(0,1,0,QM,QN) MMA_ONE(1,1,0,QM,QN) MMA_ONE(2,1,0,QM,QN) MMA_ONE(3,1,0,QM,QN) \
  MMA_ONE(0,0,1,QM,QN) MMA_ONE(1,0,1,QM,QN) MMA_ONE(2,0,1,QM,QN) MMA_ONE(3,0,1,QM,QN) \
  MMA_ONE(0,1,1,QM,QN) MMA_ONE(1,1,1,QM,QN) MMA_ONE(2,1,1,QM,QN) MMA_ONE(3,1,1,QM,QN) \
  __builtin_amdgcn_s_setprio(0); }

#define LDA(BUF, QM) { \
  const char* p_ = smemB + (BUF) * 65536 + (wm * 128 + (QM) * 64 + l15) * 128; \
  af[0][0] = *(const f16x8*)(p_ + 0*2048 + rc0); af[0][1] = *(const f16x8*)(p_ + 0*2048 + rc1); \
  af[1][0] = *(const f16x8*)(p_ + 1*2048 + rc0); af[1][1] = *(const f16x8*)(p_ + 1*2048 + rc1); \
  af[2][0] = *(const f16x8*)(p_ + 2*2048 + rc0); af[2][1] = *(const f16x8*)(p_ + 2*2048 + rc1); \
  af[3][0] = *(const f16x8*)(p_ + 3*2048 + rc0); af[3][1] = *(const f16x8*)(p_ + 3*2048 + rc1); }

#define LDB(BUF, QN) { \
  const char* p_ = smemB + (BUF) * 65536 + 32768 + (wn * 64 + (QN) * 32 + l15) * 128; \
  bf[(QN)*2+0][0] = *(const f16x8*)(p_ + 0*2048 + rc0); bf[(QN)*2+0][1] = *(const f16x8*)(p_ + 0*2048 + rc1); \
  bf[(QN)*2+1][0] = *(const f16x8*)(p_ + 1*2048 + rc0); bf[(QN)*2+1][1] = *(const f16x8*)(p_ + 1*2048 + rc1); }

#define STAGEA(TILE, Q) { \
  gload_lds16(aBase + (size_t)((Q) * 64) * 2304 + (TILE) * 64, \
              smemB + ((TILE) & 1) * 65536 + (((Q) * 64 + wv * 8) * 128)); \
  gload_lds16(aBase + (size_t)(128 + (Q) * 64) * 2304 + (TILE) * 64, \
              smemB + ((TILE) & 1) * 65536 + ((128 + (Q) * 64 + wv * 8) * 128)); }

#define STAGEB(TILE, Q, PPX0, PPX1) { \
  int j_ = (TILE) >> 2; \
  int offp_ = (j_ / 3 - 1) * PCOL + (j_ % 3) - 1; \
  int cb_ = ((TILE) & 3) * 64; \
  int rs_ = (wv >> 2) * 64 + (Q) * 32 + (wv & 3) * 8; \
  gload_lds16(bBase + (size_t)((PPX0) + offp_) * CC + cb_, \
              smemB + ((TILE) & 1) * 65536 + 32768 + (rs_ * 128)); \
  gload_lds16(bBase + (size_t)((PPX1) + offp_) * CC + cb_, \
              smemB + ((TILE) & 1) * 65536 + 32768 + ((128 + rs_) * 128)); }

__global__ void __launch_bounds__(512) k_conv3_mfma8(
    const _Float16* __restrict__ qpad, const _Float16* __restrict__ Whf,
    const float* __restrict__ Ball, unsigned int* __restrict__ taprec) {
  int nb = blockIdx.x;        // 36 px tiles of 256
  int z = blockIdx.y;         // 6 = 3 d x 2 b
  int d = z >> 1, b = z & 1;
  int t = threadIdx.x;
  int lane = t & 63, wv = t >> 6;        // 8 waves
  int wm = wv >> 2, wn = wv & 3;         // 2 x 4 wave grid -> 128x64 per wave
  int quad = lane >> 4, l15 = lane & 15;
  int l8 = lane >> 3, c7 = lane & 7;

  __shared__ _Float16 __attribute__((aligned(16))) smem[65536];  // 128 KiB
  char* smemB = (char*)smem;

  const _Float16* Wd = Whf + (size_t)d * 256 * 2304;
  const _Float16* qb = qpad + (size_t)b * PPX * CC;

  int scol = ((c7 ^ l8) << 3);                   // source col offset (halfs)
  int rc0 = ((quad ^ (l15 & 7)) << 4);           // read byte col, k-slice 0
  int rc1 = (((4 | quad) ^ (l15 & 7)) << 4);     // k-slice 1

  const _Float16* aBase = Wd + (size_t)(wv * 8 + l8) * 2304 + scol;
  const _Float16* bBase = qb + scol;

  int ppx00, ppx01, ppx10, ppx11;
  {
    int rbase = (wv >> 2) * 64 + (wv & 3) * 8 + l8;
    int px, hh, ww;
    px = nb * 256 + rbase;             hh = px / 96; ww = px - hh * 96; ppx00 = (hh + 4) * PCOL + ww + 4;
    px = nb * 256 + 128 + rbase;       hh = px / 96; ww = px - hh * 96; ppx01 = (hh + 4) * PCOL + ww + 4;
    px = nb * 256 + 32 + rbase;        hh = px / 96; ww = px - hh * 96; ppx10 = (hh + 4) * PCOL + ww + 4;
    px = nb * 256 + 160 + rbase;       hh = px / 96; ww = px - hh * 96; ppx11 = (hh + 4) * PCOL + ww + 4;
  }

  f32x4 acc[8][4];
  #pragma unroll
  for (int i = 0; i < 8; ++i)
    #pragma unroll
    for (int j = 0; j < 4; ++j) acc[i][j] = (f32x4){0.f, 0.f, 0.f, 0.f};

  f16x8 af[4][2], bf[4][2];

  STAGEA(0, 0);
  STAGEB(0, 1, ppx10, ppx11);
  STAGEA(0, 1);
  STAGEB(0, 0, ppx00, ppx01);
  STAGEA(1, 0);
  STAGEB(1, 1, ppx10, ppx11);
  VMCNT(4);
  BAR();
  SCHEDB();

  #pragma unroll 1
  for (int ii = 0; ii < 17; ++ii) {
    int ta = 2 * ii + 1, tb = 2 * ii + 2, tc = 2 * ii + 3;
    LDA(0, 0) LDB(0, 0)
    STAGEA(ta, 1);
    BAR(); MMA_Q(0, 0); BAR();
    LDB(0, 1)
    STAGEB(ta, 0, ppx00, ppx01);
    BAR(); MMA_Q(0, 1); BAR();
    LDA(0, 1)
    STAGEA(tb, 0);
    BAR(); MMA_Q(1, 1); BAR();
    STAGEB(tb, 1, ppx10, ppx11);
    VMCNT(4);
    BAR(); SCHEDB(); MMA_Q(1, 0); BAR();
    LDA(1, 0) LDB(1, 0)
    STAGEA(tb, 1);
    BAR(); MMA_Q(0, 0); BAR();
    LDB(1, 1)
    STAGEB(tb, 0, ppx00, ppx01);
    BAR(); MMA_Q(0, 1); BAR();
    LDA(1, 1)
    STAGEA(tc, 0);
    BAR(); MMA_Q(1, 1); BAR();
    STAGEB(tc, 1, ppx10, ppx11);
    VMCNT(4);
    BAR(); SCHEDB(); MMA_Q(1, 0); BAR();
  }

  LDA(0, 0) LDB(0, 0)
  STAGEA(35, 1);
  BAR(); MMA_Q(0, 0); BAR();
  LDB(0, 1)
  STAGEB(35, 0, ppx00, ppx01);
  BAR(); MMA_Q(0, 1); BAR();
  LDA(0, 1)
  BAR(); MMA_Q(1, 1); BAR();
  VMCNT(0);
  BAR(); SCHEDB(); MMA_Q(1, 0); BAR();
  LDA(1, 0) LDB(1, 0)
  BAR(); MMA_Q(0, 0); BAR();
  LDB(1, 1)
  BAR(); MMA_Q(0, 1); BAR();
  LDA(1, 1)
  BAR(); MMA_Q(1, 1); BAR();
  MMA_Q(1, 0);

  // ---------------- fused taps epilogue ----------------
  BAR();
  float* cs = (float*)smemB;
  const float* Bd = Ball + d * 256;
  unsigned int* tzo = taprec + (size_t)z * 72 * HW * 3;
  int sub = t & 7;
  int pxq = t >> 3;            // 0..63
  int dil = 1 << d;

  #pragma unroll 1
  for (int H = 0; H < 2; ++H) {
    if ((wn >> 1) == H) {
      #pragma unroll
      for (int mi = 0; mi < 8; ++mi) {
        int c2 = wm * 128 + mi * 16 + quad * 4;
        if (c2 < 216) {
          float4 bq = *(const float4*)(Bd + c2);
          #pragma unroll
          for (int ni = 0; ni < 4; ++ni) {
            int pl = (wn & 1) * 64 + ni * 16 + l15;
            f32x4 v = acc[mi][ni];
            float* cp = &cs[pl * 225 + c2];
            cp[0] = v[0] + bq.x; cp[1] = v[1] + bq.y;
            cp[2] = v[2] + bq.z; cp[3] = v[3] + bq.w;
          }
        }
      }
    }
    BAR();
    #pragma unroll 1
    for (int p = 0; p < 2; ++p) {
      int pl = p * 64 + pxq;                       // 0..127
      int px = nb * 256 + H * 128 + pl;
      const float* cr = &cs[pl * 225];
      float lg[9];
      float mx = -1e30f;
      #pragma unroll
      for (int j = 0; j < 9; ++j) {
        lg[j] = cr[144 + sub + 8 * j];
        mx = fmaxf(mx, lg[j]);
      }
      mx = fmaxf(mx, __shfl_xor(mx, 1));
      mx = fmaxf(mx, __shfl_xor(mx, 2));
      mx = fmaxf(mx, __shfl_xor(mx, 4));
      float s = 0.f;
      #pragma unroll
      for (int j = 0; j < 9; ++j) s += __expf(lg[j] - mx);
      s += __shfl_xor(s, 1);
      s += __shfl_xor(s, 2);
      s += __shfl_xor(s, 4);
      float rinv = 1.f / s;
      int h = px / WWID, w = px - h * WWID;
      int k = sub;               // k = tk % 9, tk = sub + 8j
      #pragma unroll
      for (int j = 0; j < 9; ++j) {
        int tk = sub + 8 * j;
        float dy = cr[tk * 2 + 0];
        float dx = cr[tk * 2 + 1];
        float m = __expf(lg[j] - mx) * rinv;
        float py = (float)(h + (k / 3) * dil - dil) + dy;
        float pxx = (float)(w + (k % 3) * dil - dil) + dx;
        float y0f = floorf(py), x0f = floorf(pxx);
        int y0 = (int)y0f, x0 = (int)x0f;
        float wy = py - y0f, wx = pxx - x0f;
        bool vy0 = (unsigned)y0 < 96u, vy1 = (unsigned)(y0 + 1) < 96u;
        bool vx0 = (unsigned)x0 < 96u, vx1 = (unsigned)(x0 + 1) < 96u;
        float w00 = (vy0 && vx0) ? (1.f - wy) * (1.f - wx) * m : 0.f;
        float w01 = (vy0 && vx1) ? (1.f - wy) * wx * m : 0.f;
        float w10 = (vy1 && vx0) ? wy * (1.f - wx) * m : 0.f;
        float w11 = (vy1 && vx1) ? wy * wx * m : 0.f;
        int iy = min(max(y0 + 4, 0), 102);
        int ix = min(max(x0 + 4, 0), 126);
        unsigned int* r = tzo + ((size_t)tk * HW + px) * 3;
        r[0] = pack2h(w00, w01);
        r[1] = pack2h(w10, w11);
        r[2] = (unsigned int)(iy * PCOL + ix);
        k += 8; if (k >= 9) k -= 9;
      }
    }
    BAR();
  }
}

// deformable conv v8 (reverted from v9): LDS-staged records read as
// ds_read_b128, 2 ch/lane dword gathers, 2 og passes, XCD slab swizzle.
#define DO_P(U0, U1, IDX, P) { \
  h2v u0_ = __builtin_bit_cast(h2v, (U0)); \
  h2v u1_ = __builtin_bit_cast(h2v, (U1)); \
  const h2v* b0_ = qc + (size_t)(IDX) * 128; \
  h2v q00_ = b0_[0], q01_ = b0_[128]; \
  h2v q10_ = b0_[16384], q11_ = b0_[16384 + 128]; \
  h2v s_ = q00_ * (h2v){u0_.x, u0_.x} + q01_ * (h2v){u0_.y, u0_.y} \
         + q10_ * (h2v){u1_.x, u1_.x} + q11_ * (h2v){u1_.y, u1_.y}; \
  acc[P][0] = FDOT2(wr0, s_, acc[P][0]); \
  acc[P][1] = FDOT2(wr1, s_, acc[P][1]); \
  acc[P][2] = FDOT2(wr2, s_, acc[P][2]); }

__global__ void __launch_bounds__(256) k_deform(
    const _Float16* __restrict__ qpad, const unsigned int* __restrict__ taprec,
    const float* __restrict__ s_ln, float* __restrict__ sim) {
  // linear grid 3456 = 8 slabs (XCD via dispatch round-robin) x 432
  int bid = blockIdx.x;
  int slab = bid & 7;
  int j = bid >> 3;                    // 0..431
  int z = j / 72;                      // 6
  int rem = j - z * 72;
  int yhalf = rem / 36;                // 0: og 0..3, 1: og 4..7
  int segin = rem - yhalf * 36;        // 36
  int seg = slab * 36 + segin;         // 288 px segments of 32
  int d_idx = z >> 1, b = z & 1;
  int t = threadIdx.x;
  int g = t >> 5, lane = t & 31;
  int half16 = lane >> 4, l16 = lane & 15;
  __shared__ _Float16 wh[9 * 384];         // half of the weights: [9 k][384 ch]
  __shared__ unsigned int __attribute__((aligned(16))) rlds[36 * 96];  // [36 tk][32 px x 3]
  int px0 = seg * 32;
  int tkbase = yhalf * 36;
  const unsigned int* tz = taprec + (size_t)z * 72 * HW * 3;
  for (int i2 = t; i2 < 3456; i2 += 256) {
    int c = i2 / 9, k = i2 % 9;
    wh[k * 384 + c] = (_Float16)s_ln[(size_t)b * 6912 + yhalf * 3456 + i2];
  }
  for (int i2 = t; i2 < 3456; i2 += 256) {
    int tko = i2 / 96, dw = i2 - tko * 96;
    rlds[i2] = tz[((size_t)(tkbase + tko) * HW + px0) * 3 + dw];
  }
  __syncthreads();
  int pg = g * 4;
  int pxb = px0 + pg;
  const unsigned int* whd = (const unsigned int*)wh;
  const _Float16* qb = qpad + (size_t)b * PPX * CC;

  float acc[4][3];
  #pragma unroll
  for (int p = 0; p < 4; ++p)
    #pragma unroll
    for (int r = 0; r < 3; ++r) acc[p][r] = 0.f;

  #pragma unroll 1
  for (int ogp = 0; ogp < 2; ++ogp) {
    int og = yhalf * 4 + ogp * 2 + half16;
    int qch = og * 32 + l16 * 2;          // q channel (even)
    int wcol = qch - yhalf * 128;         // 0..126 within the 384-col half
    int tko = (ogp * 2 + half16) * 9;     // tk - tkbase
    const h2v* qc = (const h2v*)(qb + qch);
    #pragma unroll 3
    for (int k = 0; k < 9; ++k) {
      const uint4* rr4 = (const uint4*)&rlds[(tko + k) * 96 + pg * 3];
      uint4 ra = rr4[0];
      uint4 rb = rr4[1];
      uint4 rc = rr4[2];
      h2v wr0 = __builtin_bit_cast(h2v, whd[(k * 384 + 0 + wcol) >> 1]);
      h2v wr1 = __builtin_bit_cast(h2v, whd[(k * 384 + 128 + wcol) >> 1]);
      h2v wr2 = __builtin_bit_cast(h2v, whd[(k * 384 + 256 + wcol) >> 1]);
      DO_P(ra.x, ra.y, ra.z, 0)
      DO_P(ra.w, rb.x, rb.y, 1)
      DO_P(rb.z, rb.w, rc.x, 2)
      DO_P(rc.y, rc.z, rc.w, 3)
    }
  }

  #pragma unroll
  for (int p = 0; p < 4; ++p) {
    #pragma unroll
    for (int r = 0; r < 3; ++r) {
      float v = acc[p][r];
      #pragma unroll
      for (int off = 16; off; off >>= 1) v += __shfl_down(v, off, 32);
      if (lane == 0)
        sim[((size_t)b * 24 + 6 + 6 * d_idx + yhalf * 3 + r) * HW + pxb + p] = v;
    }
  }
}

// out 1x1 conv: 4 co per block -> 4x sim-read reuse. grid (36, 64, B).
__global__ void k_outconv(const float* __restrict__ sim, const float* __restrict__ out_w,
                          const float* __restrict__ out_b, float* __restrict__ out) {
  int hw = blockIdx.x * 256 + threadIdx.x;
  int coq = blockIdx.y * 4;
  int b = blockIdx.z;
  const float* simb = sim + (size_t)b * 24 * HW;
  float a0 = out_b[coq + 0];
  float a1 = out_b[coq + 1];
  float a2 = out_b[coq + 2];
  float a3 = out_b[coq + 3];
  #pragma unroll
  for (int r = 0; r < 24; ++r) {
    float sv = simb[(size_t)r * HW + hw];
    a0 += out_w[(coq + 0) * 24 + r] * sv;
    a1 += out_w[(coq + 1) * 24 + r] * sv;
    a2 += out_w[(coq + 2) * 24 + r] * sv;
    a3 += out_w[(coq + 3) * 24 + r] * sv;
  }
  size_t base = ((size_t)b * CC + coq) * HW + hw;
  out[base] = a0;
  out[base + HW] = a1;
  out[base + 2 * HW] = a2;
  out[base + 3 * HW] = a3;
}

extern "C" void kernel_launch(void* const* d_in, const int* in_sizes, int n_in,
                              void* d_out, int out_size, void* d_ws, size_t ws_size,
                              hipStream_t stream) {
  const float* querys = (const float*)d_in[0];
  const float* sup    = (const float*)d_in[1];
  const float* in_w   = (const float*)d_in[2];
  const float* in_b   = (const float*)d_in[3];
  const float* ln_g   = (const float*)d_in[4];
  const float* ln_b   = (const float*)d_in[5];
  const float* out_w  = (const float*)d_in[6];
  const float* out_b  = (const float*)d_in[7];
  const float* ow1 = (const float*)d_in[8];
  const float* ob1 = (const float*)d_in[9];
  const float* mw1 = (const float*)d_in[10];
  const float* mb1 = (const float*)d_in[11];
  const float* ow2 = (const float*)d_in[12];
  const float* ob2 = (const float*)d_in[13];
  const float* mw2 = (const float*)d_in[14];
  const float* mb2 = (const float*)d_in[15];
  const float* ow4 = (const float*)d_in[16];
  const float* ob4 = (const float*)d_in[17];
  const float* mw4 = (const float*)d_in[18];
  const float* mb4 = (const float*)d_in[19];
  float* out = (float*)d_out;

  float* ws_f   = (float*)d_ws;
  float* wT     = ws_f;                              // 65536 floats
  _Float16* Whf = (_Float16*)(wT + 65536);           // 884736 float slots
  float* Ball   = (float*)(Whf + 3 * 256 * 2304);    // 768 (pad 1024)
  _Float16* qpad = (_Float16*)(Ball + 1024);         // 3407872 float slots
  float* s_ln   = (float*)(qpad + (size_t)BB * PPX * CC);  // 13824
  float* pooled = s_ln + 13824;                      // 1536
  unsigned int* taprec = (unsigned int*)(pooled + 1536);   // 11943936 dwords
  float* sim    = (float*)(taprec + (size_t)6 * 72 * HW * 3);  // 442368

  hipMemsetAsync(qpad, 0, (size_t)BB * PPX * CC * sizeof(_Float16), stream);
  k_prep<<<dim3(256 + 1728), dim3(256), 0, stream>>>(
      in_w, wT, ow1, ob1, mw1, mb1, ow2, ob2, mw2, mb2, ow4, ob4, mw4, mb4, Whf, Ball);
  k_conv1_ln_s<<<dim3(6), dim3(256), 0, stream>>>(sup, wT, in_b, ln_g, ln_b, s_ln, pooled);
  k_conv1_ln_q<<<dim3(576), dim3(256), 0, stream>>>(querys, wT, in_b, ln_g, ln_b, pooled, qpad, sim);
  k_conv3_mfma8<<<dim3(36, 6), dim3(512), 0, stream>>>(qpad, Whf, Ball, taprec);
  k_deform<<<dim3(3456), dim3(256), 0, stream>>>(qpad, taprec, s_ln, sim);
  k_outconv<<<dim3(36, 64, BB), dim3(256), 0, stream>>>(sim, out_w, out_b, out);
}